// Round 11
// baseline (419.593 us; speedup 1.0000x reference)
//
#include <hip/hip_runtime.h>

#define D 128
#define EPSBN 1e-5f
#define GROWS 64
#define GBK 64

typedef __attribute__((ext_vector_type(8))) short bf16x8;
typedef __attribute__((ext_vector_type(4))) float f32x4;

static __device__ __forceinline__ unsigned short f2b(float f) {
    unsigned u = __float_as_uint(f);
    unsigned r = u + 0x7FFF + ((u >> 16) & 1);   // RNE
    return (unsigned short)(r >> 16);
}
static __device__ __forceinline__ float b2f_lo(unsigned p) { return __uint_as_float(p << 16); }
static __device__ __forceinline__ float b2f_hi(unsigned p) { return __uint_as_float(p & 0xFFFF0000u); }

// fp16 <-> fp32 (RNE) via _Float16
static __device__ __forceinline__ unsigned short f2h(float f) {
    _Float16 h = (_Float16)f;
    unsigned short u;
    __builtin_memcpy(&u, &h, 2);
    return u;
}
static __device__ __forceinline__ float h2f(unsigned short u) {
    _Float16 h;
    __builtin_memcpy(&h, &u, 2);
    return (float)h;
}
static __device__ __forceinline__ float h2f_lo(unsigned p) { return h2f((unsigned short)(p & 0xFFFF)); }
static __device__ __forceinline__ float h2f_hi(unsigned p) { return h2f((unsigned short)(p >> 16)); }

// ---------------- setup kernels ----------------

__global__ void k_deg(const int* __restrict__ ei, int E, int* __restrict__ deg,
                      int* __restrict__ pos) {
    int e = blockIdx.x * 256 + threadIdx.x;
    if (e < E) pos[e] = atomicAdd(&deg[ei[E + e]], 1);
}

__global__ void k_bsum(const int* __restrict__ deg, int* __restrict__ bsum, int N) {
    __shared__ int sm[256];
    int t = threadIdx.x, v = blockIdx.x * 256 + t;
    sm[t] = (v < N) ? deg[v] : 0;
    __syncthreads();
    for (int off = 128; off > 0; off >>= 1) {
        if (t < off) sm[t] += sm[t + off];
        __syncthreads();
    }
    if (t == 0) bsum[blockIdx.x] = sm[0];
}

__global__ void k_bscan(const int* __restrict__ bsum, int* __restrict__ boff,
                        int* __restrict__ row_ptr, int NB, int N, int E) {
    __shared__ int sm[256];
    int t = threadIdx.x;
    int v = (t < NB) ? bsum[t] : 0;
    sm[t] = v;
    __syncthreads();
    for (int off = 1; off < 256; off <<= 1) {
        int x = (t >= off) ? sm[t - off] : 0;
        __syncthreads();
        sm[t] += x;
        __syncthreads();
    }
    if (t < NB) boff[t] = sm[t] - v;
    if (t == 0) row_ptr[N] = E;
}

__global__ void k_scatter(const int* __restrict__ deg, const int* __restrict__ boff,
                          int* __restrict__ row_ptr, int N) {
    __shared__ int sm[256];
    int t = threadIdx.x, v = blockIdx.x * 256 + t;
    int val = (v < N) ? deg[v] : 0;
    sm[t] = val;
    __syncthreads();
    for (int off = 1; off < 256; off <<= 1) {
        int x = (t >= off) ? sm[t - off] : 0;
        __syncthreads();
        sm[t] += x;
        __syncthreads();
    }
    if (v < N) row_ptr[v] = boff[blockIdx.x] + sm[t] - val;
}

// atomic-free CSR placement using precomputed ranks
__global__ void k_place(const int* __restrict__ ei, const int* __restrict__ row_ptr,
                        const int* __restrict__ pos, int2* __restrict__ csr, int E) {
    int e = blockIdx.x * 256 + threadIdx.x;
    if (e >= E) return;
    int c = ei[E + e];
    csr[row_ptr[c] + pos[e]] = make_int2(ei[e], e);
}

// cvals[v] = sum nm_e * attr[e]; rewrites csr[j] = (src, nm). rsqrt(deg) inline.
__global__ void k_cvals(const int* __restrict__ row_ptr, int2* __restrict__ csr,
                        const int* __restrict__ deg, const float* __restrict__ attr,
                        float4* __restrict__ cvals, int N) {
    int v = blockIdx.x * 256 + threadIdx.x;
    if (v >= N) return;
    int dgv = deg[v];
    float dv = (dgv > 0) ? rsqrtf((float)dgv) : 0.f;
    int jb = row_ptr[v], je = row_ptr[v + 1];
    float4 acc = make_float4(0.f, 0.f, 0.f, 0.f);
    for (int j = jb; j < je; ++j) {
        int2 e = csr[j];
        int dgs = deg[e.x];
        float ds = (dgs > 0) ? rsqrtf((float)dgs) : 0.f;
        float nm = ds * dv;
        float4 a = *(const float4*)(attr + (size_t)e.y * 4);
        acc.x += nm * a.x; acc.y += nm * a.y;
        acc.z += nm * a.z; acc.w += nm * a.w;
        csr[j] = make_int2(e.x, __float_as_int(nm));
    }
    cvals[v] = acc;
}

// fp32 -> bf16 pack (4 elems / thread)
__global__ void k_cvt(const float* __restrict__ in, unsigned short* __restrict__ outp, int n4) {
    int i = blockIdx.x * 256 + threadIdx.x;
    if (i >= n4) return;
    float4 v = *(const float4*)(in + (size_t)i * 4);
    ushort4 p;
    p.x = f2b(v.x); p.y = f2b(v.y); p.z = f2b(v.z); p.w = f2b(v.w);
    *(ushort4*)(outp + (size_t)i * 4) = p;
}

// ---------------- per-layer kernels ----------------

// 2 nodes per wave (32 lanes each), 2 quarters x 4 slots = 8 edges in
// flight per node. csr=(src,nm). apply=0: hb bf16 x. apply=1: hb fp16
// pre-norm h2; sc/sh computed inline from raw stats_prev + gam/bet of the
// producing layer. Block 0 zeroes stats_cur for this layer's gemm.
__global__ __launch_bounds__(256) void k_spmm(
        const unsigned short* __restrict__ hb, const int* __restrict__ row_ptr,
        const int2* __restrict__ csr, const float4* __restrict__ cvals,
        const float* __restrict__ W1l, const float* __restrict__ W2l,
        const float* __restrict__ stats_prev, float* __restrict__ stats_cur,
        const float* __restrict__ gam_p, const float* __restrict__ bet_p,
        int apply, unsigned short* __restrict__ aggb, int N) {
    if (blockIdx.x == 0) stats_cur[threadIdx.x] = 0.f;
    int lane = threadIdx.x & 63;
    int wave = threadIdx.x >> 6;
    int nh = lane >> 5;                 // node half 0/1
    int v = blockIdx.x * 8 + wave * 2 + nh;
    if (v >= N) return;
    int qw = (lane >> 4) & 1;           // quarter within half
    int l4 = lane & 15;
    int d0 = l4 * 8;
    int jb = row_ptr[v], je = row_ptr[v + 1];

    float a[8];
#pragma unroll
    for (int i = 0; i < 8; ++i) a[i] = 0.f;

    if (apply) {
        float sc[8], sh[8];
        float rn = 1.0f / (float)N;
#pragma unroll
        for (int i = 0; i < 8; ++i) {
            int n = d0 + i;
            float mean = stats_prev[n] * rn;
            float var = fmaxf(stats_prev[D + n] * rn - mean * mean, 0.f);
            sc[i] = gam_p[n] * rsqrtf(var + EPSBN);
            sh[i] = bet_p[n] - mean * sc[i];
        }
        for (int j0 = jb; j0 < je; j0 += 8) {
            int2 e[4]; float nm[4]; uint4 p[4];
#pragma unroll
            for (int s = 0; s < 4; ++s) {
                int j = j0 + 2 * s + qw;
                bool ok = (j < je);
                e[s] = csr[ok ? j : jb];
                nm[s] = ok ? __int_as_float(e[s].y) : 0.f;
            }
#pragma unroll
            for (int s = 0; s < 4; ++s)
                p[s] = *(const uint4*)(hb + (size_t)e[s].x * D + d0);
#pragma unroll
            for (int s = 0; s < 4; ++s) {
                float xv[8] = {h2f_lo(p[s].x), h2f_hi(p[s].x), h2f_lo(p[s].y), h2f_hi(p[s].y),
                               h2f_lo(p[s].z), h2f_hi(p[s].z), h2f_lo(p[s].w), h2f_hi(p[s].w)};
#pragma unroll
                for (int i = 0; i < 8; ++i)
                    a[i] += nm[s] * fmaxf(sc[i] * xv[i] + sh[i], 0.f);
            }
        }
    } else {
        for (int j0 = jb; j0 < je; j0 += 8) {
            int2 e[4]; float nm[4]; uint4 p[4];
#pragma unroll
            for (int s = 0; s < 4; ++s) {
                int j = j0 + 2 * s + qw;
                bool ok = (j < je);
                e[s] = csr[ok ? j : jb];
                nm[s] = ok ? __int_as_float(e[s].y) : 0.f;
            }
#pragma unroll
            for (int s = 0; s < 4; ++s)
                p[s] = *(const uint4*)(hb + (size_t)e[s].x * D + d0);
#pragma unroll
            for (int s = 0; s < 4; ++s) {
                a[0] += nm[s] * b2f_lo(p[s].x); a[1] += nm[s] * b2f_hi(p[s].x);
                a[2] += nm[s] * b2f_lo(p[s].y); a[3] += nm[s] * b2f_hi(p[s].y);
                a[4] += nm[s] * b2f_lo(p[s].z); a[5] += nm[s] * b2f_hi(p[s].z);
                a[6] += nm[s] * b2f_lo(p[s].w); a[7] += nm[s] * b2f_hi(p[s].w);
            }
        }
    }
    // fold the 2 quarters within each 32-lane half
#pragma unroll
    for (int i = 0; i < 8; ++i) a[i] += __shfl_xor(a[i], 16);

    if (qw == 0) {
        float4 c = cvals[v];
        float4 wa0 = *(const float4*)(W1l + d0);
        float4 wa1 = *(const float4*)(W1l + d0 + 4);
        float4 wb0 = *(const float4*)(W1l + D + d0);
        float4 wb1 = *(const float4*)(W1l + D + d0 + 4);
        float4 wc0 = *(const float4*)(W1l + 2 * D + d0);
        float4 wc1 = *(const float4*)(W1l + 2 * D + d0 + 4);
        float4 wd0 = *(const float4*)(W2l + d0);
        float4 wd1 = *(const float4*)(W2l + d0 + 4);
        a[0] += c.x * wa0.x + c.y * wb0.x + c.z * wc0.x + c.w * wd0.x;
        a[1] += c.x * wa0.y + c.y * wb0.y + c.z * wc0.y + c.w * wd0.y;
        a[2] += c.x * wa0.z + c.y * wb0.z + c.z * wc0.z + c.w * wd0.z;
        a[3] += c.x * wa0.w + c.y * wb0.w + c.z * wc0.w + c.w * wd0.w;
        a[4] += c.x * wa1.x + c.y * wb1.x + c.z * wc1.x + c.w * wd1.x;
        a[5] += c.x * wa1.y + c.y * wb1.y + c.z * wc1.y + c.w * wd1.y;
        a[6] += c.x * wa1.z + c.y * wb1.z + c.z * wc1.z + c.w * wd1.z;
        a[7] += c.x * wa1.w + c.y * wb1.w + c.z * wc1.w + c.w * wd1.w;
        uint4 o;
        o.x = ((unsigned)f2b(a[1]) << 16) | (unsigned)f2b(a[0]);
        o.y = ((unsigned)f2b(a[3]) << 16) | (unsigned)f2b(a[2]);
        o.z = ((unsigned)f2b(a[5]) << 16) | (unsigned)f2b(a[4]);
        o.w = ((unsigned)f2b(a[7]) << 16) | (unsigned)f2b(a[6]);
        *(uint4*)(aggb + (size_t)v * D + d0) = o;
    }
}

// h2 = relu([h, agg] @ Wmb^T + bm) via bf16 MFMA, 2 row-tiles per block.
// apply: affine from stats_prev+gam/bet precomputed into LDS. Output fp16
// pre-norm h2; raw per-column sum/sumsq folded and atomicAdd'ed to stats_cur.
__global__ __launch_bounds__(256) void k_gemm(
        const unsigned short* __restrict__ hsrc, const unsigned short* __restrict__ aggb,
        const unsigned short* __restrict__ Wmb, const float* __restrict__ bml,
        const float* __restrict__ stats_prev, float* __restrict__ stats_cur,
        const float* __restrict__ gam_p, const float* __restrict__ bet_p,
        int apply, unsigned short* __restrict__ h2h, int N) {
    __shared__ unsigned short As[2][GROWS][GBK + 8];
    __shared__ unsigned short Bs[D][GBK + 8];
    __shared__ float sred[2][4][D];
    __shared__ float scsh_l[2 * D];
    int tid = threadIdx.x;
    int lane = tid & 63, wave = tid >> 6;
    int n0a = blockIdx.x * (2 * GROWS);
    int l15 = lane & 15, q = lane >> 4;

    if (apply && tid < D) {
        float rn = 1.0f / (float)N;
        float mean = stats_prev[tid] * rn;
        float var = fmaxf(stats_prev[D + tid] * rn - mean * mean, 0.f);
        float sc = gam_p[tid] * rsqrtf(var + EPSBN);
        scsh_l[tid] = sc;
        scsh_l[D + tid] = bet_p[tid] - mean * sc;
    }
    if (apply) __syncthreads();

    f32x4 acc[2][8];
#pragma unroll
    for (int t2 = 0; t2 < 2; ++t2)
#pragma unroll
        for (int t = 0; t < 8; ++t) acc[t2][t] = (f32x4){0.f, 0.f, 0.f, 0.f};

    for (int kc = 0; kc < 4; ++kc) {
        const unsigned short* src = (kc < 2) ? hsrc : aggb;
        bool aff = (kc < 2) && apply;
        int k0 = (kc & 1) * GBK;
#pragma unroll
        for (int t2 = 0; t2 < 2; ++t2) {
#pragma unroll
            for (int i = 0; i < 2; ++i) {
                int idx = tid + i * 256;
                int r = idx >> 3, seg = idx & 7;
                int m = n0a + t2 * GROWS + r;
                uint4 val = make_uint4(0u, 0u, 0u, 0u);
                if (m < N) val = *(const uint4*)(src + (size_t)m * D + k0 + seg * 8);
                if (aff) {
                    int db = k0 + seg * 8;
                    float4 s0 = *(const float4*)(scsh_l + db);
                    float4 s1 = *(const float4*)(scsh_l + db + 4);
                    float4 t0 = *(const float4*)(scsh_l + D + db);
                    float4 t1 = *(const float4*)(scsh_l + D + db + 4);
                    float e0 = fmaxf(s0.x * h2f_lo(val.x) + t0.x, 0.f);
                    float e1 = fmaxf(s0.y * h2f_hi(val.x) + t0.y, 0.f);
                    float e2 = fmaxf(s0.z * h2f_lo(val.y) + t0.z, 0.f);
                    float e3 = fmaxf(s0.w * h2f_hi(val.y) + t0.w, 0.f);
                    float e4 = fmaxf(s1.x * h2f_lo(val.z) + t1.x, 0.f);
                    float e5 = fmaxf(s1.y * h2f_hi(val.z) + t1.y, 0.f);
                    float e6 = fmaxf(s1.z * h2f_lo(val.w) + t1.z, 0.f);
                    float e7 = fmaxf(s1.w * h2f_hi(val.w) + t1.w, 0.f);
                    val.x = ((unsigned)f2b(e1) << 16) | (unsigned)f2b(e0);
                    val.y = ((unsigned)f2b(e3) << 16) | (unsigned)f2b(e2);
                    val.z = ((unsigned)f2b(e5) << 16) | (unsigned)f2b(e4);
                    val.w = ((unsigned)f2b(e7) << 16) | (unsigned)f2b(e6);
                }
                *(uint4*)&As[t2][r][seg * 8] = val;
            }
        }
#pragma unroll
        for (int i = 0; i < 4; ++i) {
            int idx = tid + i * 256;
            int n = idx >> 3, seg = idx & 7;
            *(uint4*)&Bs[n][seg * 8] =
                *(const uint4*)(Wmb + (size_t)n * 256 + kc * GBK + seg * 8);
        }
        __syncthreads();
#pragma unroll
        for (int s = 0; s < 2; ++s) {
            bf16x8 a0 = *(const bf16x8*)&As[0][wave * 16 + l15][s * 32 + q * 8];
            bf16x8 a1 = *(const bf16x8*)&As[1][wave * 16 + l15][s * 32 + q * 8];
#pragma unroll
            for (int t = 0; t < 8; ++t) {
                bf16x8 b = *(const bf16x8*)&Bs[t * 16 + l15][s * 32 + q * 8];
                acc[0][t] = __builtin_amdgcn_mfma_f32_16x16x32_bf16(a0, b, acc[0][t], 0, 0, 0);
                acc[1][t] = __builtin_amdgcn_mfma_f32_16x16x32_bf16(a1, b, acc[1][t], 0, 0, 0);
            }
        }
        __syncthreads();
    }
    float ps[8], pq[8];
#pragma unroll
    for (int t = 0; t < 8; ++t) { ps[t] = 0.f; pq[t] = 0.f; }
#pragma unroll
    for (int t2 = 0; t2 < 2; ++t2) {
        int n0 = n0a + t2 * GROWS;
        bool full = (n0 + GROWS <= N);
#pragma unroll
        for (int t = 0; t < 8; ++t) {
            int n = t * 16 + l15;
            float bias = bml[n];
#pragma unroll
            for (int r = 0; r < 4; ++r) {
                int m = n0 + wave * 16 + q * 4 + r;
                float v = fmaxf(acc[t2][t][r] + bias, 0.f);
                if (full || m < N) {
                    h2h[(size_t)m * D + n] = f2h(v);
                    ps[t] += v; pq[t] += v * v;
                }
            }
        }
    }
#pragma unroll
    for (int t = 0; t < 8; ++t) {
        ps[t] += __shfl_xor(ps[t], 16); ps[t] += __shfl_xor(ps[t], 32);
        pq[t] += __shfl_xor(pq[t], 16); pq[t] += __shfl_xor(pq[t], 32);
    }
    if (q == 0) {
#pragma unroll
        for (int t = 0; t < 8; ++t) {
            sred[0][wave][t * 16 + l15] = ps[t];
            sred[1][wave][t * 16 + l15] = pq[t];
        }
    }
    __syncthreads();
    if (tid < D) {
        float s = sred[0][0][tid] + sred[0][1][tid] + sred[0][2][tid] + sred[0][3][tid];
        atomicAdd(&stats_cur[tid], s);
    } else {
        int n = tid - D;
        float qv = sred[1][0][n] + sred[1][1][n] + sred[1][2][n] + sred[1][3][n];
        atomicAdd(&stats_cur[D + n], qv);
    }
}

// final output: out = sc*h2 + sh (fp32, no relu); sc/sh from raw stats
__global__ void k_norm_last(const unsigned short* __restrict__ h2h,
                            const float* __restrict__ stats,
                            const float* __restrict__ gam_p, const float* __restrict__ bet_p,
                            float* __restrict__ out_f, int total4, int N) {
    int i = blockIdx.x * 256 + threadIdx.x;
    if (i >= total4) return;
    int base = i * 4;
    int d = base & (D - 1);
    float rn = 1.0f / (float)N;
    float sc[4], sh[4];
#pragma unroll
    for (int k = 0; k < 4; ++k) {
        int n = d + k;
        float mean = stats[n] * rn;
        float var = fmaxf(stats[D + n] * rn - mean * mean, 0.f);
        sc[k] = gam_p[n] * rsqrtf(var + EPSBN);
        sh[k] = bet_p[n] - mean * sc[k];
    }
    uint2 p = *(const uint2*)(h2h + base);
    float4 o;
    o.x = sc[0] * h2f_lo(p.x) + sh[0];
    o.y = sc[1] * h2f_hi(p.x) + sh[1];
    o.z = sc[2] * h2f_lo(p.y) + sh[2];
    o.w = sc[3] * h2f_hi(p.y) + sh[3];
    *(float4*)(out_f + base) = o;
}

// ---------------- host launcher ----------------

extern "C" void kernel_launch(void* const* d_in, const int* in_sizes, int n_in,
                              void* d_out, int out_size, void* d_ws, size_t ws_size,
                              hipStream_t stream) {
    const float* x    = (const float*)d_in[0];
    const int*   ei   = (const int*)d_in[1];
    const float* attr = (const float*)d_in[2];
    const float* W1   = (const float*)d_in[3];
    const float* W2   = (const float*)d_in[4];
    const float* Wm   = (const float*)d_in[5];
    const float* bm   = (const float*)d_in[6];
    const float* gam  = (const float*)d_in[7];
    const float* bet  = (const float*)d_in[8];
    float* out = (float*)d_out;

    const int N = in_sizes[0] / D;
    const int E = in_sizes[1] / 2;
    const int L = in_sizes[3] / (3 * D);
    const int NB = (N + 255) / 256;

    size_t off = 0;
    auto carve = [&](size_t bytes) {
        void* p = (char*)d_ws + off;
        off += (bytes + 255) & ~(size_t)255;
        return p;
    };
    int*            deg     = (int*)carve((size_t)N * 4);
    int*            row_ptr = (int*)carve((size_t)(N + 1) * 4);
    int*            pos     = (int*)carve((size_t)E * 4);
    int*            bsum    = (int*)carve((size_t)NB * 4);
    int*            boff    = (int*)carve((size_t)NB * 4);
    int2*           csr     = (int2*)carve((size_t)(E + 8) * 8);
    float4*         cvals   = (float4*)carve((size_t)N * 16);
    unsigned short* xb      = (unsigned short*)carve((size_t)N * D * 2);
    unsigned short* h2h     = (unsigned short*)carve((size_t)N * D * 2);   // fp16 pre-norm h2
    unsigned short* aggb    = (unsigned short*)carve((size_t)N * D * 2);
    unsigned short* Wmb     = (unsigned short*)carve((size_t)L * D * 256 * 2);
    float*          stats   = (float*)carve((size_t)2 * 2 * D * 4);        // double-buffered raw sums
    (void)ws_size;

    hipMemsetAsync(deg, 0, (size_t)N * 4, stream);

    const int eb = (E + 255) / 256;
    k_deg<<<eb, 256, 0, stream>>>(ei, E, deg, pos);
    k_bsum<<<NB, 256, 0, stream>>>(deg, bsum, N);
    k_bscan<<<1, 256, 0, stream>>>(bsum, boff, row_ptr, NB, N, E);
    k_scatter<<<NB, 256, 0, stream>>>(deg, boff, row_ptr, N);
    k_place<<<eb, 256, 0, stream>>>(ei, row_ptr, pos, csr, E);
    k_cvals<<<NB, 256, 0, stream>>>(row_ptr, csr, deg, attr, cvals, N);

    const int xq = N * D / 4;
    k_cvt<<<(xq + 255) / 256, 256, 0, stream>>>(x, xb, xq);
    const int wq = L * D * 256 / 4;
    k_cvt<<<(wq + 255) / 256, 256, 0, stream>>>(Wm, Wmb, wq);

    const int total4 = N * D / 4;
    const int gemmb = (N + 2 * GROWS - 1) / (2 * GROWS);
    const int spmmb = (N + 7) / 8;

    for (int l = 0; l < L; ++l) {
        const unsigned short* in = (l == 0) ? xb : h2h;
        const int apply = (l > 0) ? 1 : 0;
        const float* W1l = W1 + (size_t)l * 3 * D;
        const float* W2l = W2 + (size_t)l * D;
        const unsigned short* Wml = Wmb + (size_t)l * D * 256;
        const float* bml = bm + (size_t)l * D;
        float* stats_cur = stats + (size_t)(l & 1) * 2 * D;
        const float* stats_prev = stats + (size_t)((l ^ 1) & 1) * 2 * D;
        const float* gam_p = gam + (size_t)(l > 0 ? l - 1 : 0) * D;
        const float* bet_p = bet + (size_t)(l > 0 ? l - 1 : 0) * D;

        k_spmm<<<spmmb, 256, 0, stream>>>(in, row_ptr, csr, cvals, W1l, W2l,
                                          stats_prev, stats_cur, gam_p, bet_p,
                                          apply, aggb, N);
        k_gemm<<<gemmb, 256, 0, stream>>>(in, aggb, Wml, bml,
                                          stats_prev, stats_cur, gam_p, bet_p,
                                          apply, h2h, N);
    }
    k_norm_last<<<(total4 + 255) / 256, 256, 0, stream>>>(
        h2h, stats + (size_t)((L - 1) & 1) * 2 * D,
        gam + (size_t)(L - 1) * D, bet + (size_t)(L - 1) * D, out, total4, N);
}

// Round 12
// 413.204 us; speedup vs baseline: 1.0155x; 1.0155x over previous
//
#include <hip/hip_runtime.h>

#define D 128
#define EPSBN 1e-5f
#define GROWS 64
#define GBK 64

typedef __attribute__((ext_vector_type(8))) short bf16x8;
typedef __attribute__((ext_vector_type(4))) float f32x4;

static __device__ __forceinline__ unsigned short f2b(float f) {
    unsigned u = __float_as_uint(f);
    unsigned r = u + 0x7FFF + ((u >> 16) & 1);   // RNE
    return (unsigned short)(r >> 16);
}
static __device__ __forceinline__ float b2f_lo(unsigned p) { return __uint_as_float(p << 16); }
static __device__ __forceinline__ float b2f_hi(unsigned p) { return __uint_as_float(p & 0xFFFF0000u); }

// fp16 <-> fp32 (RNE) via _Float16
static __device__ __forceinline__ unsigned short f2h(float f) {
    _Float16 h = (_Float16)f;
    unsigned short u;
    __builtin_memcpy(&u, &h, 2);
    return u;
}
static __device__ __forceinline__ float h2f(unsigned short u) {
    _Float16 h;
    __builtin_memcpy(&h, &u, 2);
    return (float)h;
}
static __device__ __forceinline__ float h2f_lo(unsigned p) { return h2f((unsigned short)(p & 0xFFFF)); }
static __device__ __forceinline__ float h2f_hi(unsigned p) { return h2f((unsigned short)(p >> 16)); }

// ---------------- setup kernels ----------------

__global__ void k_deg(const int* __restrict__ ei, int E, int* __restrict__ deg,
                      int* __restrict__ pos) {
    int e = blockIdx.x * 256 + threadIdx.x;
    if (e < E) pos[e] = atomicAdd(&deg[ei[E + e]], 1);
}

__global__ void k_bsum(const int* __restrict__ deg, int* __restrict__ bsum, int N) {
    __shared__ int sm[256];
    int t = threadIdx.x, v = blockIdx.x * 256 + t;
    sm[t] = (v < N) ? deg[v] : 0;
    __syncthreads();
    for (int off = 128; off > 0; off >>= 1) {
        if (t < off) sm[t] += sm[t + off];
        __syncthreads();
    }
    if (t == 0) bsum[blockIdx.x] = sm[0];
}

__global__ void k_bscan(const int* __restrict__ bsum, int* __restrict__ boff,
                        int* __restrict__ row_ptr, int NB, int N, int E) {
    __shared__ int sm[256];
    int t = threadIdx.x;
    int v = (t < NB) ? bsum[t] : 0;
    sm[t] = v;
    __syncthreads();
    for (int off = 1; off < 256; off <<= 1) {
        int x = (t >= off) ? sm[t - off] : 0;
        __syncthreads();
        sm[t] += x;
        __syncthreads();
    }
    if (t < NB) boff[t] = sm[t] - v;
    if (t == 0) row_ptr[N] = E;
}

__global__ void k_scatter(const int* __restrict__ deg, const int* __restrict__ boff,
                          int* __restrict__ row_ptr, int N) {
    __shared__ int sm[256];
    int t = threadIdx.x, v = blockIdx.x * 256 + t;
    int val = (v < N) ? deg[v] : 0;
    sm[t] = val;
    __syncthreads();
    for (int off = 1; off < 256; off <<= 1) {
        int x = (t >= off) ? sm[t - off] : 0;
        __syncthreads();
        sm[t] += x;
        __syncthreads();
    }
    if (v < N) row_ptr[v] = boff[blockIdx.x] + sm[t] - val;
}

// atomic-free CSR placement using precomputed ranks
__global__ void k_place(const int* __restrict__ ei, const int* __restrict__ row_ptr,
                        const int* __restrict__ pos, int2* __restrict__ csr, int E) {
    int e = blockIdx.x * 256 + threadIdx.x;
    if (e >= E) return;
    int c = ei[E + e];
    csr[row_ptr[c] + pos[e]] = make_int2(ei[e], e);
}

// cvals[v] = sum nm_e * attr[e]; rewrites csr[j] = (src, nm). rsqrt(deg) inline.
__global__ void k_cvals(const int* __restrict__ row_ptr, int2* __restrict__ csr,
                        const int* __restrict__ deg, const float* __restrict__ attr,
                        float4* __restrict__ cvals, int N) {
    int v = blockIdx.x * 256 + threadIdx.x;
    if (v >= N) return;
    int dgv = deg[v];
    float dv = (dgv > 0) ? rsqrtf((float)dgv) : 0.f;
    int jb = row_ptr[v], je = row_ptr[v + 1];
    float4 acc = make_float4(0.f, 0.f, 0.f, 0.f);
    for (int j = jb; j < je; ++j) {
        int2 e = csr[j];
        int dgs = deg[e.x];
        float ds = (dgs > 0) ? rsqrtf((float)dgs) : 0.f;
        float nm = ds * dv;
        float4 a = *(const float4*)(attr + (size_t)e.y * 4);
        acc.x += nm * a.x; acc.y += nm * a.y;
        acc.z += nm * a.z; acc.w += nm * a.w;
        csr[j] = make_int2(e.x, __float_as_int(nm));
    }
    cvals[v] = acc;
}

// fp32 -> bf16 pack (4 elems / thread)
__global__ void k_cvt(const float* __restrict__ in, unsigned short* __restrict__ outp, int n4) {
    int i = blockIdx.x * 256 + threadIdx.x;
    if (i >= n4) return;
    float4 v = *(const float4*)(in + (size_t)i * 4);
    ushort4 p;
    p.x = f2b(v.x); p.y = f2b(v.y); p.z = f2b(v.z); p.w = f2b(v.w);
    *(ushort4*)(outp + (size_t)i * 4) = p;
}

// ---------------- per-layer kernels ----------------

// 2 nodes per wave (32 lanes each): 2 quarters x 2 slots = 4 edges in
// flight per node (R10 measured-good shape). csr=(src,nm).
// apply=0: hb bf16 x. apply=1: hb fp16 pre-norm h2; sc/sh computed inline
// from raw stats_prev + gam/bet of producing layer.
// Block 0 zeroes stats_cur for this layer's gemm (stream-ordered).
__global__ __launch_bounds__(256) void k_spmm(
        const unsigned short* __restrict__ hb, const int* __restrict__ row_ptr,
        const int2* __restrict__ csr, const float4* __restrict__ cvals,
        const float* __restrict__ W1l, const float* __restrict__ W2l,
        const float* __restrict__ stats_prev, float* __restrict__ stats_cur,
        const float* __restrict__ gam_p, const float* __restrict__ bet_p,
        int apply, unsigned short* __restrict__ aggb, int N) {
    if (blockIdx.x == 0) stats_cur[threadIdx.x] = 0.f;
    int lane = threadIdx.x & 63;
    int wave = threadIdx.x >> 6;
    int nh = lane >> 5;                 // node half 0/1
    int v = blockIdx.x * 8 + wave * 2 + nh;
    if (v >= N) return;
    int qw = (lane >> 4) & 1;           // quarter within half
    int l4 = lane & 15;
    int d0 = l4 * 8;
    int jb = row_ptr[v], je = row_ptr[v + 1];

    float a[8];
#pragma unroll
    for (int i = 0; i < 8; ++i) a[i] = 0.f;

    if (apply) {
        float sc[8], sh[8];
        float rn = 1.0f / (float)N;
#pragma unroll
        for (int i = 0; i < 8; ++i) {
            int n = d0 + i;
            float mean = stats_prev[n] * rn;
            float var = fmaxf(stats_prev[D + n] * rn - mean * mean, 0.f);
            sc[i] = gam_p[n] * rsqrtf(var + EPSBN);
            sh[i] = bet_p[n] - mean * sc[i];
        }
        for (int j0 = jb; j0 < je; j0 += 4) {
            int ja = j0 + qw, jc = j0 + 2 + qw;
            bool oa = (ja < je), oc = (jc < je);
            int2 ea = csr[oa ? ja : jb];
            int2 ec = csr[oc ? jc : jb];
            float na = oa ? __int_as_float(ea.y) : 0.f;
            float nc = oc ? __int_as_float(ec.y) : 0.f;
            uint4 pa = *(const uint4*)(hb + (size_t)ea.x * D + d0);
            uint4 pc = *(const uint4*)(hb + (size_t)ec.x * D + d0);
            float xa[8] = {h2f_lo(pa.x), h2f_hi(pa.x), h2f_lo(pa.y), h2f_hi(pa.y),
                           h2f_lo(pa.z), h2f_hi(pa.z), h2f_lo(pa.w), h2f_hi(pa.w)};
            float xc[8] = {h2f_lo(pc.x), h2f_hi(pc.x), h2f_lo(pc.y), h2f_hi(pc.y),
                           h2f_lo(pc.z), h2f_hi(pc.z), h2f_lo(pc.w), h2f_hi(pc.w)};
#pragma unroll
            for (int i = 0; i < 8; ++i) {
                a[i] += na * fmaxf(sc[i] * xa[i] + sh[i], 0.f);
                a[i] += nc * fmaxf(sc[i] * xc[i] + sh[i], 0.f);
            }
        }
    } else {
        for (int j0 = jb; j0 < je; j0 += 4) {
            int ja = j0 + qw, jc = j0 + 2 + qw;
            bool oa = (ja < je), oc = (jc < je);
            int2 ea = csr[oa ? ja : jb];
            int2 ec = csr[oc ? jc : jb];
            float na = oa ? __int_as_float(ea.y) : 0.f;
            float nc = oc ? __int_as_float(ec.y) : 0.f;
            uint4 pa = *(const uint4*)(hb + (size_t)ea.x * D + d0);
            uint4 pc = *(const uint4*)(hb + (size_t)ec.x * D + d0);
            a[0] += na * b2f_lo(pa.x) + nc * b2f_lo(pc.x);
            a[1] += na * b2f_hi(pa.x) + nc * b2f_hi(pc.x);
            a[2] += na * b2f_lo(pa.y) + nc * b2f_lo(pc.y);
            a[3] += na * b2f_hi(pa.y) + nc * b2f_hi(pc.y);
            a[4] += na * b2f_lo(pa.z) + nc * b2f_lo(pc.z);
            a[5] += na * b2f_hi(pa.z) + nc * b2f_hi(pc.z);
            a[6] += na * b2f_lo(pa.w) + nc * b2f_lo(pc.w);
            a[7] += na * b2f_hi(pa.w) + nc * b2f_hi(pc.w);
        }
    }
    // fold the 2 quarters within each 32-lane half
#pragma unroll
    for (int i = 0; i < 8; ++i) a[i] += __shfl_xor(a[i], 16);

    if (qw == 0) {
        float4 c = cvals[v];
        float4 wa0 = *(const float4*)(W1l + d0);
        float4 wa1 = *(const float4*)(W1l + d0 + 4);
        float4 wb0 = *(const float4*)(W1l + D + d0);
        float4 wb1 = *(const float4*)(W1l + D + d0 + 4);
        float4 wc0 = *(const float4*)(W1l + 2 * D + d0);
        float4 wc1 = *(const float4*)(W1l + 2 * D + d0 + 4);
        float4 wd0 = *(const float4*)(W2l + d0);
        float4 wd1 = *(const float4*)(W2l + d0 + 4);
        a[0] += c.x * wa0.x + c.y * wb0.x + c.z * wc0.x + c.w * wd0.x;
        a[1] += c.x * wa0.y + c.y * wb0.y + c.z * wc0.y + c.w * wd0.y;
        a[2] += c.x * wa0.z + c.y * wb0.z + c.z * wc0.z + c.w * wd0.z;
        a[3] += c.x * wa0.w + c.y * wb0.w + c.z * wc0.w + c.w * wd0.w;
        a[4] += c.x * wa1.x + c.y * wb1.x + c.z * wc1.x + c.w * wd1.x;
        a[5] += c.x * wa1.y + c.y * wb1.y + c.z * wc1.y + c.w * wd1.y;
        a[6] += c.x * wa1.z + c.y * wb1.z + c.z * wc1.z + c.w * wd1.z;
        a[7] += c.x * wa1.w + c.y * wb1.w + c.z * wc1.w + c.w * wd1.w;
        uint4 o;
        o.x = ((unsigned)f2b(a[1]) << 16) | (unsigned)f2b(a[0]);
        o.y = ((unsigned)f2b(a[3]) << 16) | (unsigned)f2b(a[2]);
        o.z = ((unsigned)f2b(a[5]) << 16) | (unsigned)f2b(a[4]);
        o.w = ((unsigned)f2b(a[7]) << 16) | (unsigned)f2b(a[6]);
        *(uint4*)(aggb + (size_t)v * D + d0) = o;
    }
}

// h2 = relu([h, agg] @ Wmb^T + bm) via bf16 MFMA, 2 row-tiles per block.
// apply: affine from stats_prev+gam/bet precomputed into LDS. Output fp16
// pre-norm h2; raw per-column sum/sumsq folded and atomicAdd'ed to stats_cur.
__global__ __launch_bounds__(256) void k_gemm(
        const unsigned short* __restrict__ hsrc, const unsigned short* __restrict__ aggb,
        const unsigned short* __restrict__ Wmb, const float* __restrict__ bml,
        const float* __restrict__ stats_prev, float* __restrict__ stats_cur,
        const float* __restrict__ gam_p, const float* __restrict__ bet_p,
        int apply, unsigned short* __restrict__ h2h, int N) {
    __shared__ unsigned short As[2][GROWS][GBK + 8];
    __shared__ unsigned short Bs[D][GBK + 8];
    __shared__ float sred[2][4][D];
    __shared__ float scsh_l[2 * D];
    int tid = threadIdx.x;
    int lane = tid & 63, wave = tid >> 6;
    int n0a = blockIdx.x * (2 * GROWS);
    int l15 = lane & 15, q = lane >> 4;

    if (apply && tid < D) {
        float rn = 1.0f / (float)N;
        float mean = stats_prev[tid] * rn;
        float var = fmaxf(stats_prev[D + tid] * rn - mean * mean, 0.f);
        float sc = gam_p[tid] * rsqrtf(var + EPSBN);
        scsh_l[tid] = sc;
        scsh_l[D + tid] = bet_p[tid] - mean * sc;
    }
    if (apply) __syncthreads();

    f32x4 acc[2][8];
#pragma unroll
    for (int t2 = 0; t2 < 2; ++t2)
#pragma unroll
        for (int t = 0; t < 8; ++t) acc[t2][t] = (f32x4){0.f, 0.f, 0.f, 0.f};

    for (int kc = 0; kc < 4; ++kc) {
        const unsigned short* src = (kc < 2) ? hsrc : aggb;
        bool aff = (kc < 2) && apply;
        int k0 = (kc & 1) * GBK;
#pragma unroll
        for (int t2 = 0; t2 < 2; ++t2) {
#pragma unroll
            for (int i = 0; i < 2; ++i) {
                int idx = tid + i * 256;
                int r = idx >> 3, seg = idx & 7;
                int m = n0a + t2 * GROWS + r;
                uint4 val = make_uint4(0u, 0u, 0u, 0u);
                if (m < N) val = *(const uint4*)(src + (size_t)m * D + k0 + seg * 8);
                if (aff) {
                    int db = k0 + seg * 8;
                    float4 s0 = *(const float4*)(scsh_l + db);
                    float4 s1 = *(const float4*)(scsh_l + db + 4);
                    float4 t0 = *(const float4*)(scsh_l + D + db);
                    float4 t1 = *(const float4*)(scsh_l + D + db + 4);
                    float e0 = fmaxf(s0.x * h2f_lo(val.x) + t0.x, 0.f);
                    float e1 = fmaxf(s0.y * h2f_hi(val.x) + t0.y, 0.f);
                    float e2 = fmaxf(s0.z * h2f_lo(val.y) + t0.z, 0.f);
                    float e3 = fmaxf(s0.w * h2f_hi(val.y) + t0.w, 0.f);
                    float e4 = fmaxf(s1.x * h2f_lo(val.z) + t1.x, 0.f);
                    float e5 = fmaxf(s1.y * h2f_hi(val.z) + t1.y, 0.f);
                    float e6 = fmaxf(s1.z * h2f_lo(val.w) + t1.z, 0.f);
                    float e7 = fmaxf(s1.w * h2f_hi(val.w) + t1.w, 0.f);
                    val.x = ((unsigned)f2b(e1) << 16) | (unsigned)f2b(e0);
                    val.y = ((unsigned)f2b(e3) << 16) | (unsigned)f2b(e2);
                    val.z = ((unsigned)f2b(e5) << 16) | (unsigned)f2b(e4);
                    val.w = ((unsigned)f2b(e7) << 16) | (unsigned)f2b(e6);
                }
                *(uint4*)&As[t2][r][seg * 8] = val;
            }
        }
#pragma unroll
        for (int i = 0; i < 4; ++i) {
            int idx = tid + i * 256;
            int n = idx >> 3, seg = idx & 7;
            *(uint4*)&Bs[n][seg * 8] =
                *(const uint4*)(Wmb + (size_t)n * 256 + kc * GBK + seg * 8);
        }
        __syncthreads();
#pragma unroll
        for (int s = 0; s < 2; ++s) {
            bf16x8 a0 = *(const bf16x8*)&As[0][wave * 16 + l15][s * 32 + q * 8];
            bf16x8 a1 = *(const bf16x8*)&As[1][wave * 16 + l15][s * 32 + q * 8];
#pragma unroll
            for (int t = 0; t < 8; ++t) {
                bf16x8 b = *(const bf16x8*)&Bs[t * 16 + l15][s * 32 + q * 8];
                acc[0][t] = __builtin_amdgcn_mfma_f32_16x16x32_bf16(a0, b, acc[0][t], 0, 0, 0);
                acc[1][t] = __builtin_amdgcn_mfma_f32_16x16x32_bf16(a1, b, acc[1][t], 0, 0, 0);
            }
        }
        __syncthreads();
    }
    float ps[8], pq[8];
#pragma unroll
    for (int t = 0; t < 8; ++t) { ps[t] = 0.f; pq[t] = 0.f; }
#pragma unroll
    for (int t2 = 0; t2 < 2; ++t2) {
        int n0 = n0a + t2 * GROWS;
        bool full = (n0 + GROWS <= N);
#pragma unroll
        for (int t = 0; t < 8; ++t) {
            int n = t * 16 + l15;
            float bias = bml[n];
#pragma unroll
            for (int r = 0; r < 4; ++r) {
                int m = n0 + wave * 16 + q * 4 + r;
                float v = fmaxf(acc[t2][t][r] + bias, 0.f);
                if (full || m < N) {
                    h2h[(size_t)m * D + n] = f2h(v);
                    ps[t] += v; pq[t] += v * v;
                }
            }
        }
    }
#pragma unroll
    for (int t = 0; t < 8; ++t) {
        ps[t] += __shfl_xor(ps[t], 16); ps[t] += __shfl_xor(ps[t], 32);
        pq[t] += __shfl_xor(pq[t], 16); pq[t] += __shfl_xor(pq[t], 32);
    }
    if (q == 0) {
#pragma unroll
        for (int t = 0; t < 8; ++t) {
            sred[0][wave][t * 16 + l15] = ps[t];
            sred[1][wave][t * 16 + l15] = pq[t];
        }
    }
    __syncthreads();
    if (tid < D) {
        float s = sred[0][0][tid] + sred[0][1][tid] + sred[0][2][tid] + sred[0][3][tid];
        atomicAdd(&stats_cur[tid], s);
    } else {
        int n = tid - D;
        float qv = sred[1][0][n] + sred[1][1][n] + sred[1][2][n] + sred[1][3][n];
        atomicAdd(&stats_cur[D + n], qv);
    }
}

// final output: out = sc*h2 + sh (fp32, no relu); sc/sh from raw stats
__global__ void k_norm_last(const unsigned short* __restrict__ h2h,
                            const float* __restrict__ stats,
                            const float* __restrict__ gam_p, const float* __restrict__ bet_p,
                            float* __restrict__ out_f, int total4, int N) {
    int i = blockIdx.x * 256 + threadIdx.x;
    if (i >= total4) return;
    int base = i * 4;
    int d = base & (D - 1);
    float rn = 1.0f / (float)N;
    float sc[4], sh[4];
#pragma unroll
    for (int k = 0; k < 4; ++k) {
        int n = d + k;
        float mean = stats[n] * rn;
        float var = fmaxf(stats[D + n] * rn - mean * mean, 0.f);
        sc[k] = gam_p[n] * rsqrtf(var + EPSBN);
        sh[k] = bet_p[n] - mean * sc[k];
    }
    uint2 p = *(const uint2*)(h2h + base);
    float4 o;
    o.x = sc[0] * h2f_lo(p.x) + sh[0];
    o.y = sc[1] * h2f_hi(p.x) + sh[1];
    o.z = sc[2] * h2f_lo(p.y) + sh[2];
    o.w = sc[3] * h2f_hi(p.y) + sh[3];
    *(float4*)(out_f + base) = o;
}

// ---------------- host launcher ----------------

extern "C" void kernel_launch(void* const* d_in, const int* in_sizes, int n_in,
                              void* d_out, int out_size, void* d_ws, size_t ws_size,
                              hipStream_t stream) {
    const float* x    = (const float*)d_in[0];
    const int*   ei   = (const int*)d_in[1];
    const float* attr = (const float*)d_in[2];
    const float* W1   = (const float*)d_in[3];
    const float* W2   = (const float*)d_in[4];
    const float* Wm   = (const float*)d_in[5];
    const float* bm   = (const float*)d_in[6];
    const float* gam  = (const float*)d_in[7];
    const float* bet  = (const float*)d_in[8];
    float* out = (float*)d_out;

    const int N = in_sizes[0] / D;
    const int E = in_sizes[1] / 2;
    const int L = in_sizes[3] / (3 * D);
    const int NB = (N + 255) / 256;

    size_t off = 0;
    auto carve = [&](size_t bytes) {
        void* p = (char*)d_ws + off;
        off += (bytes + 255) & ~(size_t)255;
        return p;
    };
    int*            deg     = (int*)carve((size_t)N * 4);
    int*            row_ptr = (int*)carve((size_t)(N + 1) * 4);
    int*            pos     = (int*)carve((size_t)E * 4);
    int*            bsum    = (int*)carve((size_t)NB * 4);
    int*            boff    = (int*)carve((size_t)NB * 4);
    int2*           csr     = (int2*)carve((size_t)(E + 8) * 8);
    float4*         cvals   = (float4*)carve((size_t)N * 16);
    unsigned short* xb      = (unsigned short*)carve((size_t)N * D * 2);
    unsigned short* h2h     = (unsigned short*)carve((size_t)N * D * 2);   // fp16 pre-norm h2
    unsigned short* aggb    = (unsigned short*)carve((size_t)N * D * 2);
    unsigned short* Wmb     = (unsigned short*)carve((size_t)L * D * 256 * 2);
    float*          stats   = (float*)carve((size_t)2 * 2 * D * 4);        // double-buffered raw sums
    (void)ws_size;

    hipMemsetAsync(deg, 0, (size_t)N * 4, stream);

    const int eb = (E + 255) / 256;
    k_deg<<<eb, 256, 0, stream>>>(ei, E, deg, pos);
    k_bsum<<<NB, 256, 0, stream>>>(deg, bsum, N);
    k_bscan<<<1, 256, 0, stream>>>(bsum, boff, row_ptr, NB, N, E);
    k_scatter<<<NB, 256, 0, stream>>>(deg, boff, row_ptr, N);
    k_place<<<eb, 256, 0, stream>>>(ei, row_ptr, pos, csr, E);
    k_cvals<<<NB, 256, 0, stream>>>(row_ptr, csr, deg, attr, cvals, N);

    const int xq = N * D / 4;
    k_cvt<<<(xq + 255) / 256, 256, 0, stream>>>(x, xb, xq);
    const int wq = L * D * 256 / 4;
    k_cvt<<<(wq + 255) / 256, 256, 0, stream>>>(Wm, Wmb, wq);

    const int total4 = N * D / 4;
    const int gemmb = (N + 2 * GROWS - 1) / (2 * GROWS);
    const int spmmb = (N + 7) / 8;

    for (int l = 0; l < L; ++l) {
        const unsigned short* in = (l == 0) ? xb : h2h;
        const int apply = (l > 0) ? 1 : 0;
        const float* W1l = W1 + (size_t)l * 3 * D;
        const float* W2l = W2 + (size_t)l * D;
        const unsigned short* Wml = Wmb + (size_t)l * D * 256;
        const float* bml = bm + (size_t)l * D;
        float* stats_cur = stats + (size_t)(l & 1) * 2 * D;
        const float* stats_prev = stats + (size_t)((l ^ 1) & 1) * 2 * D;
        const float* gam_p = gam + (size_t)(l > 0 ? l - 1 : 0) * D;
        const float* bet_p = bet + (size_t)(l > 0 ? l - 1 : 0) * D;

        k_spmm<<<spmmb, 256, 0, stream>>>(in, row_ptr, csr, cvals, W1l, W2l,
                                          stats_prev, stats_cur, gam_p, bet_p,
                                          apply, aggb, N);
        k_gemm<<<gemmb, 256, 0, stream>>>(in, aggb, Wml, bml,
                                          stats_prev, stats_cur, gam_p, bet_p,
                                          apply, h2h, N);
    }
    k_norm_last<<<(total4 + 255) / 256, 256, 0, stream>>>(
        h2h, stats + (size_t)((L - 1) & 1) * 2 * D,
        gam + (size_t)(L - 1) * D, bet + (size_t)(L - 1) * D, out, total4, N);
}